// Round 13
// baseline (206.096 us; speedup 1.0000x reference)
//
#include <hip/hip_runtime.h>
#include <type_traits>

#define S_LEN 2048
#define HID   768
#define NHEAD 12
#define HDIM  64
#define BATCH 4

typedef __attribute__((ext_vector_type(4))) float float4v;
typedef __attribute__((ext_vector_type(8))) short short8;
typedef __attribute__((ext_vector_type(4))) short short4v;
typedef __attribute__((ext_vector_type(2))) int int2v;

__device__ __forceinline__ short f2b(float f) {
  unsigned u = __float_as_uint(f);
  u += 0x7fff + ((u >> 16) & 1);   // RNE
  return (short)(u >> 16);
}

__device__ __forceinline__ unsigned pkbf(float a, float b) {
#if __has_builtin(__builtin_amdgcn_cvt_pk_bf16_f32)
  typedef __attribute__((ext_vector_type(2))) __bf16 bf2;
  bf2 r = __builtin_amdgcn_cvt_pk_bf16_f32(a, b);
  return *(unsigned*)&r;
#else
  return ((unsigned)(unsigned short)f2b(a)) |
         (((unsigned)(unsigned short)f2b(b)) << 16);
#endif
}

__device__ __forceinline__ float fexp2(float x) {
#if __has_builtin(__builtin_amdgcn_exp2f)
  return __builtin_amdgcn_exp2f(x);
#else
  return __expf(x * 0.69314718056f);
#endif
}

// async global->LDS, 16 B per lane; lds base must be wave-uniform
__device__ __forceinline__ void g2l16(const short* g, short* l) {
  __builtin_amdgcn_global_load_lds(
      (const __attribute__((address_space(1))) void*)g,
      (__attribute__((address_space(3))) void*)l, 16, 0, 0);
}

// ---------------- fused pre-pass: cvt x + transpose both weights ----------------
__global__ __launch_bounds__(256) void prepass(const float* __restrict__ x,
                                               const float* __restrict__ w_qkv,
                                               const float* __restrict__ w_out,
                                               short* __restrict__ xb,
                                               short* __restrict__ wqkvT,
                                               short* __restrict__ woutT) {
  __shared__ float tile[64][65];
  const int blk = blockIdx.x;
  if (blk < 3072) {  // cvt: 2048 elems per block
    int i = blk * 2048 + threadIdx.x * 8;
    float4v a = *(const float4v*)&x[i];
    float4v b = *(const float4v*)&x[i + 4];
    short8 o;
#pragma unroll
    for (int j = 0; j < 4; j++) { o[j] = f2b(a[j]); o[j + 4] = f2b(b[j]); }
    *(short8*)&xb[i] = o;
    return;
  }
  const float* W; short* WT; int N_, scaleN, idx;
  if (blk < 3504) { idx = blk - 3072; W = w_qkv; WT = wqkvT; N_ = 3 * HID; scaleN = HID; }
  else            { idx = blk - 3504; W = w_out; WT = woutT; N_ = HID;     scaleN = 0;  }
  const int nblk = N_ / 64;
  const int n0 = (idx % nblk) * 64, k0 = (idx / nblk) * 64;
  const int tx = threadIdx.x & 63, ty = threadIdx.x >> 6;
#pragma unroll
  for (int r = 0; r < 16; r++) {
    int row = r * 4 + ty;
    tile[row][tx] = W[(size_t)(k0 + row) * N_ + n0 + tx];
  }
  __syncthreads();
#pragma unroll
  for (int r = 0; r < 16; r++) {
    int row = r * 4 + ty;
    float sc = (n0 + row < scaleN) ? 0.18033688011f : 1.0f;  // 0.125*log2e
    WT[(size_t)(n0 + row) * HID + k0 + tx] = f2b(tile[tx][row] * sc);
  }
}

// ---------------- bf16 GEMM: C[MxN] = A[MxK] * Bt[NxK]^T ----------
// FULL REVERT to the r6-proven structure (stage 8 loads, sync, compute
// BK=64, sync).  r4 and r10 both showed pipeline restructures regress:
// these grids (768/384 blocks) are fully co-resident, so inter-block wave
// overlap already hides DMA latency; counted-vmcnt triple-buffering only
// cost LDS occupancy (5->3 blocks/CU) for -9us.
//   * LDS slot XOR-swizzle (pre-swizzled global source, lane-constant
//     read slot) -> 2 lanes/bank, conflicts ~0 (verified r6).
//   * OUT: 0 = float C, 1 = Q/K bf16, 2 = V with swapped MFMA operands
//     (transposed acc -> vT[d][s] stores land along s; traffic-verified r4).
//   * XCD-chunked block swizzle (nwg%8==0 all launches).
template <int OUT>
__global__ __launch_bounds__(256) void gemm_bt(const short* __restrict__ A,
                                               const short* __restrict__ Bt,
                                               float* __restrict__ Cf,
                                               short* __restrict__ Cq,
                                               short* __restrict__ vT,
                                               int M, int N, int K) {
  __shared__ __align__(16) short As[2][128 * 32];
  __shared__ __align__(16) short Bs[2][128 * 32];
  const int tid = threadIdx.x;
  const int w = tid >> 6, lane = tid & 63;
  const int quad = lane >> 4, lm = lane & 15;

  const int gx = gridDim.x;
  const int nwg = gx * gridDim.y;
  int flat = blockIdx.y * gx + blockIdx.x;
  if ((nwg & 7) == 0) flat = (flat & 7) * (nwg >> 3) + (flat >> 3);
  const int m0 = (flat / gx) * 128, n0 = (flat % gx) * 128;
  const int mo = (w & 1) * 64, no = (w >> 1) * 64;

  float4v acc[4][4];
#pragma unroll
  for (int i = 0; i < 4; i++)
#pragma unroll
    for (int j = 0; j < 4; j++) acc[i][j] = (float4v)0.0f;

  // staging: linear LDS dest; source column chunk pre-swizzled so that
  // LDS[row][slot] holds global chunk slot^((row>>1)&3)
  const int srow = w * 32 + (lane >> 2);
  const int scol = ((lane & 3) ^ ((lane >> 3) & 3)) * 8;
  const short* Ag = A + (size_t)(m0 + srow) * K + scol;
  const short* Bg = Bt + (size_t)(n0 + srow) * K + scol;

  // read-side: lane-constant swizzled slot
  const int qsw8 = (quad ^ ((lm >> 1) & 3)) * 8;

  for (int kb = 0; kb < K; kb += 64) {
#pragma unroll
    for (int s = 0; s < 2; s++) {
      short* Al = &As[s][(w * 32) * 32];
      short* Bl = &Bs[s][(w * 32) * 32];
      g2l16(Ag + kb + s * 32, Al);
      g2l16(Ag + kb + s * 32 + (size_t)16 * K, Al + 16 * 32);
      g2l16(Bg + kb + s * 32, Bl);
      g2l16(Bg + kb + s * 32 + (size_t)16 * K, Bl + 16 * 32);
    }
    __syncthreads();

#pragma unroll
    for (int s = 0; s < 2; s++) {
      short8 af[4], bf[4];
#pragma unroll
      for (int i = 0; i < 4; i++)
        af[i] = *(const short8*)&As[s][(mo + i * 16 + lm) * 32 + qsw8];
#pragma unroll
      for (int j = 0; j < 4; j++)
        bf[j] = *(const short8*)&Bs[s][(no + j * 16 + lm) * 32 + qsw8];
#pragma unroll
      for (int i = 0; i < 4; i++)
#pragma unroll
        for (int j = 0; j < 4; j++) {
          if constexpr (OUT == 2)
            acc[i][j] = __builtin_amdgcn_mfma_f32_16x16x32_bf16(bf[j], af[i], acc[i][j], 0, 0, 0);
          else
            acc[i][j] = __builtin_amdgcn_mfma_f32_16x16x32_bf16(af[i], bf[j], acc[i][j], 0, 0, 0);
        }
    }
    __syncthreads();
  }

  if constexpr (OUT == 0) {
#pragma unroll
    for (int i = 0; i < 4; i++)
#pragma unroll
      for (int j = 0; j < 4; j++)
#pragma unroll
        for (int r = 0; r < 4; r++)
          Cf[(size_t)(m0 + mo + i * 16 + quad * 4 + r) * N + n0 + no + j * 16 + lm] =
              acc[i][j][r];
  } else if constexpr (OUT == 1) {  // Q/K tile -> qk[m][1536]
#pragma unroll
    for (int i = 0; i < 4; i++)
#pragma unroll
      for (int j = 0; j < 4; j++)
#pragma unroll
        for (int r = 0; r < 4; r++)
          Cq[(size_t)(m0 + mo + i * 16 + quad * 4 + r) * (2 * HID) + n0 + no + j * 16 + lm] =
              f2b(acc[i][j][r]);
  } else {  // V tile (swapped acc: rows=n/d, cols=m/s) -> vT[b][h][d][s]
    const int b = m0 >> 11;
#pragma unroll
    for (int i = 0; i < 4; i++) {
      const int sG = (m0 & 2047) + mo + i * 16 + lm;
#pragma unroll
      for (int j = 0; j < 4; j++) {
#pragma unroll
        for (int r = 0; r < 4; r++) {
          int col = n0 + no + j * 16 + quad * 4 + r;   // 0..767 (V block local)
          int h = col >> 6, d = col & 63;
          vT[((size_t)(b * NHEAD + h) * HDIM + d) * S_LEN + sG] = f2b(acc[i][j][r]);
        }
      }
    }
  }
}

// ---------------- MFMA flash attention (128-key staging cadence) ----
// r8 falsified "issue-bound" (occ +30% -> flat, VALU fell): the wall is the
// per-iteration sync overhead (vmcnt(0) drain + barrier skew every 64 keys,
// 528 block-iters).  This round halves the cadence: stage 128 keys (2 x 64-key
// sub-tiles) per barrier, double-buffered.  Per-iter overhead paid half as
// often; the drain now waits on loads issued a full 2-sub-tile compute phase
// earlier.  Compute body per sub-tile is byte-identical to r8.  LDS 40->72 KB
// -> 2 blocks/CU (r8 proved residency isn't binding here).
__global__ __launch_bounds__(256) void attn_mfma(const short* __restrict__ qk,
                                                 const short* __restrict__ vT,
                                                 short* __restrict__ attnout) {
  __shared__ __align__(16) short Ks[2][2][64 * 64];  // [buf][st][p][d] swizzled
  __shared__ __align__(16) short Vt[2][2][64 * 64];  // [buf][st][d][key] swizzled
  __shared__ __align__(16) short Ps[4][16 * 64];     // per-wave [m][key], swizzled

  const int tid = threadIdx.x;
  const int w = tid >> 6, lane = tid & 63;
  const int quad = lane >> 4, lm = lane & 15;
  const int bh = blockIdx.x;
  const int qt = 31 - blockIdx.y;        // longest-first dispatch order
  const int b = bh / NHEAD, h = bh % NHEAD;

  // ---- Q fragments in registers ----
  short8 aq[2];
#pragma unroll
  for (int kb = 0; kb < 2; kb++)
    aq[kb] = *(const short8*)&qk[(size_t)(b * S_LEN + qt * 64 + w * 16 + lm) * (2 * HID) +
                                 h * HDIM + kb * 32 + quad * 8];

  // ---- register constants ----
  const float4v z4 = (float4v)0.0f;       // C operand for first-kb MFMA
  short8 one8;                            // bf16 1.0 broadcast (B-frag of ones)
#pragma unroll
  for (int j = 0; j < 8; j++) one8[j] = (short)0x3F80;

  // ---- per-lane DMA source pointers (inverse swizzle + key permutation
  //      pre-applied; LDS dest linear; bump-by-constant each issue).
  //      kptr/vptr cover one 64-key sub-tile; sub-tile 1 adds +64 keys. ----
  const size_t kbase = (size_t)(b * S_LEN) * (2 * HID) + HID + h * HDIM;
  const size_t vbase = (size_t)(b * NHEAD + h) * HDIM * S_LEN;
  const short* kptr[2];
  const short* vptr[2];
#pragma unroll
  for (int i = 0; i < 2; i++) {
    int c = (w * 2 + i) * 64 + lane;       // LDS 16B-chunk index this lane writes
    int row = c >> 3, slot = c & 7;
    int q8 = slot ^ (row & 7);             // inverse-swizzled source chunk
    int key = 4 * (row & 15) + (row >> 4); // key permutation (B-frag order)
    kptr[i] = qk + kbase + (size_t)key * (2 * HID) + q8 * 8;
    vptr[i] = vT + vbase + (size_t)row * S_LEN + q8 * 8;
  }

  // stage 128 keys = 2 sub-tiles; 8 g2l16 per call
#define ISSUE(BUF)                                                              \
  {                                                                             \
    _Pragma("unroll") for (int i = 0; i < 2; i++) {                             \
      _Pragma("unroll") for (int st = 0; st < 2; st++) {                        \
        g2l16(kptr[i] + (size_t)st * 64 * (2 * HID),                            \
              &Ks[BUF][st][(w * 2 + i) * 512]);                                 \
        g2l16(vptr[i] + st * 64, &Vt[BUF][st][(w * 2 + i) * 512]);              \
      }                                                                         \
      kptr[i] += 128 * 2 * HID;                                                 \
      vptr[i] += 128;                                                           \
    }                                                                           \
  }

  // ---- hoisted LDS read/write addressing ----
  const int swx = (lm & 7) << 4;
  const int loff0 = (quad * 16) ^ swx;          // kb=0 lane part
  const int loff1 = (64 + quad * 16) ^ swx;     // kb=1 lane part
  const int rowK = lm << 7;
  const char* KsB = (const char*)&Ks[0][0][0];
  const char* VtB = (const char*)&Vt[0][0][0];
  const char* PsW = (const char*)&Ps[w][0];
  const char* pread0 = PsW + rowK + loff0;      // Ps A-frag reads
  const char* pread1 = PsW + rowK + loff1;
  char* pswa[4];                                // Ps writes (static-indexed)
#pragma unroll
  for (int r = 0; r < 4; r++) {
    int rowp = quad * 4 + r;
    pswa[r] = (char*)PsW + (rowp << 7) + ((lm * 8) ^ ((rowp & 7) << 4));
  }

  float4v o_acc[4];
#pragma unroll
  for (int nt = 0; nt < 4; nt++) o_acc[nt] = (float4v)0.0f;
  float4v o1 = (float4v)0.0f;                   // P row-sum accumulator

  const int nbt = qt + 1;                       // 64-key tiles to process
  const int nbig = (nbt + 1) >> 1;              // 128-key staged iterations
  int cur = 0;

  ISSUE(0);

  for (int big = 0; big < nbig; big++) {
    // drain our in-flight DMA for buf[cur], and fence buf[cur^1] readers
    asm volatile("s_waitcnt vmcnt(0)" ::: "memory");
    __syncthreads();
    if (big + 1 < nbig) ISSUE(cur ^ 1);

#pragma unroll
    for (int st = 0; st < 2; st++) {
      const int kt = 2 * big + st;
      if (st == 1 && kt >= nbt) break;          // odd tail: skip second sub-tile

      const int soff = (cur << 14) + (st << 13);
      const char* kB0 = KsB + soff + rowK + loff0;
      const char* kB1 = KsB + soff + rowK + loff1;
      const char* vB0 = VtB + soff + rowK + loff0;
      const char* vB1 = VtB + soff + rowK + loff1;

      float4v s_acc[4];
      __builtin_amdgcn_s_setprio(1);
#pragma unroll
      for (int nt = 0; nt < 4; nt++) {
        short8 bk = *(const short8*)(kB0 + nt * 2048);
        s_acc[nt] = __builtin_amdgcn_mfma_f32_16x16x32_bf16(aq[0], bk, z4, 0, 0, 0);
      }
#pragma unroll
      for (int nt = 0; nt < 4; nt++) {
        short8 bk = *(const short8*)(kB1 + nt * 2048);
        s_acc[nt] = __builtin_amdgcn_mfma_f32_16x16x32_bf16(aq[1], bk, s_acc[nt], 0, 0, 0);
      }
      __builtin_amdgcn_s_setprio(0);

      const bool diag = (kt == qt);
#pragma unroll
      for (int r = 0; r < 4; r++) {
        float e[4];
#pragma unroll
        for (int nt = 0; nt < 4; nt++) {
          float v = fexp2(s_acc[nt][r]);  // Q pre-scaled by 0.125*log2e
          if (diag && (4 * lm + nt > w * 16 + quad * 4 + r)) v = 0.0f;
          e[nt] = v;
        }
        int2v p2 = {(int)pkbf(e[0], e[1]), (int)pkbf(e[2], e[3])};
        *(int2v*)pswa[r] = p2;  // key = 4*lm+nt
      }

      __builtin_amdgcn_s_setprio(1);
#pragma unroll
      for (int kb = 0; kb < 2; kb++) {
        short8 ap = *(const short8*)(kb ? pread1 : pread0);
        const char* vB = kb ? vB1 : vB0;
        o1 = __builtin_amdgcn_mfma_f32_16x16x32_bf16(ap, one8, o1, 0, 0, 0);
#pragma unroll
        for (int nt = 0; nt < 4; nt++) {
          short8 bv = *(const short8*)(vB + nt * 2048);
          o_acc[nt] = __builtin_amdgcn_mfma_f32_16x16x32_bf16(ap, bv, o_acc[nt], 0, 0, 0);
        }
      }
      __builtin_amdgcn_s_setprio(0);
    }
    cur ^= 1;
  }

#pragma unroll
  for (int r = 0; r < 4; r++) {
    float inv = 1.0f / o1[r];             // row-sum from ones-MFMA (col-uniform)
    int rowg = b * S_LEN + qt * 64 + w * 16 + quad * 4 + r;
#pragma unroll
    for (int nt = 0; nt < 4; nt++)
      attnout[(size_t)rowg * HID + h * HDIM + nt * 16 + lm] =
          f2b(o_acc[nt][r] * inv);
  }
#undef ISSUE
}

extern "C" void kernel_launch(void* const* d_in, const int* in_sizes, int n_in,
                              void* d_out, int out_size, void* d_ws, size_t ws_size,
                              hipStream_t stream) {
  const float* x     = (const float*)d_in[0];
  const float* w_qkv = (const float*)d_in[1];
  const float* w_out = (const float*)d_in[2];
  float* out = (float*)d_out;

  const int M = BATCH * S_LEN;  // 8192
  short* qk     = (short*)d_ws;                       // [8192][1536] bf16
  short* attn   = qk + (size_t)M * 2 * HID;           // [8192][768]  bf16
  short* vT     = attn + (size_t)M * HID;             // [B][NH][64][2048] bf16
  short* xb     = vT + (size_t)M * HID;               // [8192][768]  bf16
  short* wqkvT  = xb + (size_t)M * HID;               // [2304][768]  bf16 (Q rows pre-scaled)
  short* woutT  = wqkvT + (size_t)(3 * HID) * HID;    // [768][768]   bf16

  prepass<<<3648, 256, 0, stream>>>(x, w_qkv, w_out, xb, wqkvT, woutT);

  // Q/K columns (N=1536): nwg = 12*64 = 768 (%8==0)
  gemm_bt<1><<<dim3(2 * HID / 128, M / 128), 256, 0, stream>>>(
      xb, wqkvT, nullptr, qk, nullptr, M, 2 * HID, HID);
  // V columns (N=768), swapped-operand MFMA: nwg = 6*64 = 384 (%8==0)
  gemm_bt<2><<<dim3(HID / 128, M / 128), 256, 0, stream>>>(
      xb, wqkvT + (size_t)(2 * HID) * HID, nullptr, nullptr, vT, M, HID, HID);
  // one q-tile per block; qt = 31-blockIdx.y -> longest blocks first
  attn_mfma<<<dim3(BATCH * NHEAD, 32), 256, 0, stream>>>(qk, vT, attn);
  gemm_bt<0><<<dim3(HID / 128, M / 128), 256, 0, stream>>>(
      attn, woutT, out, nullptr, nullptr, M, HID, HID);
}

// Round 14
// 191.848 us; speedup vs baseline: 1.0743x; 1.0743x over previous
//
#include <hip/hip_runtime.h>
#include <type_traits>

#define S_LEN 2048
#define HID   768
#define NHEAD 12
#define HDIM  64
#define BATCH 4

typedef __attribute__((ext_vector_type(4))) float float4v;
typedef __attribute__((ext_vector_type(8))) short short8;
typedef __attribute__((ext_vector_type(4))) short short4v;
typedef __attribute__((ext_vector_type(2))) int int2v;
typedef __attribute__((ext_vector_type(4))) int int4v;

__device__ __forceinline__ short f2b(float f) {
  unsigned u = __float_as_uint(f);
  u += 0x7fff + ((u >> 16) & 1);   // RNE
  return (short)(u >> 16);
}

__device__ __forceinline__ unsigned pkbf(float a, float b) {
#if __has_builtin(__builtin_amdgcn_cvt_pk_bf16_f32)
  typedef __attribute__((ext_vector_type(2))) __bf16 bf2;
  bf2 r = __builtin_amdgcn_cvt_pk_bf16_f32(a, b);
  return *(unsigned*)&r;
#else
  return ((unsigned)(unsigned short)f2b(a)) |
         (((unsigned)(unsigned short)f2b(b)) << 16);
#endif
}

__device__ __forceinline__ float fexp2(float x) {
#if __has_builtin(__builtin_amdgcn_exp2f)
  return __builtin_amdgcn_exp2f(x);
#else
  return __expf(x * 0.69314718056f);
#endif
}

// async global->LDS, 16 B per lane; lds base must be wave-uniform
__device__ __forceinline__ void g2l16(const short* g, short* l) {
  __builtin_amdgcn_global_load_lds(
      (const __attribute__((address_space(1))) void*)g,
      (__attribute__((address_space(3))) void*)l, 16, 0, 0);
}

// ---------------- fused pre-pass: cvt x + transpose both weights ----------------
__global__ __launch_bounds__(256) void prepass(const float* __restrict__ x,
                                               const float* __restrict__ w_qkv,
                                               const float* __restrict__ w_out,
                                               short* __restrict__ xb,
                                               short* __restrict__ wqkvT,
                                               short* __restrict__ woutT) {
  __shared__ float tile[64][65];
  const int blk = blockIdx.x;
  if (blk < 3072) {  // cvt: 2048 elems per block
    int i = blk * 2048 + threadIdx.x * 8;
    float4v a = *(const float4v*)&x[i];
    float4v b = *(const float4v*)&x[i + 4];
    short8 o;
#pragma unroll
    for (int j = 0; j < 4; j++) { o[j] = f2b(a[j]); o[j + 4] = f2b(b[j]); }
    *(short8*)&xb[i] = o;
    return;
  }
  const float* W; short* WT; int N_, scaleN, idx;
  if (blk < 3504) { idx = blk - 3072; W = w_qkv; WT = wqkvT; N_ = 3 * HID; scaleN = HID; }
  else            { idx = blk - 3504; W = w_out; WT = woutT; N_ = HID;     scaleN = 0;  }
  const int nblk = N_ / 64;
  const int n0 = (idx % nblk) * 64, k0 = (idx / nblk) * 64;
  const int tx = threadIdx.x & 63, ty = threadIdx.x >> 6;
#pragma unroll
  for (int r = 0; r < 16; r++) {
    int row = r * 4 + ty;
    tile[row][tx] = W[(size_t)(k0 + row) * N_ + n0 + tx];
  }
  __syncthreads();
#pragma unroll
  for (int r = 0; r < 16; r++) {
    int row = r * 4 + ty;
    float sc = (n0 + row < scaleN) ? 0.18033688011f : 1.0f;  // 0.125*log2e
    WT[(size_t)(n0 + row) * HID + k0 + tx] = f2b(tile[tx][row] * sc);
  }
}

// ---------------- bf16 GEMM: C[MxN] = A[MxK] * Bt[NxK]^T ----------
// r6-proven structure (stage 8 loads, sync, compute BK=64, sync).  r4 and
// r10 both showed pipeline restructures regress (blocks fully co-resident;
// inter-block wave overlap already hides DMA latency).
//   * LDS slot XOR-swizzle -> 2 lanes/bank, conflicts ~0 (verified r6).
//   * OUT: 0 = float C, 1 = Q/K bf16, 2 = V with swapped MFMA operands
//     (transposed acc -> vT[d][s] stores land along s; traffic-verified r4).
//   * XCD-chunked block swizzle (nwg%8==0 all launches).
template <int OUT>
__global__ __launch_bounds__(256) void gemm_bt(const short* __restrict__ A,
                                               const short* __restrict__ Bt,
                                               float* __restrict__ Cf,
                                               short* __restrict__ Cq,
                                               short* __restrict__ vT,
                                               int M, int N, int K) {
  __shared__ __align__(16) short As[2][128 * 32];
  __shared__ __align__(16) short Bs[2][128 * 32];
  const int tid = threadIdx.x;
  const int w = tid >> 6, lane = tid & 63;
  const int quad = lane >> 4, lm = lane & 15;

  const int gx = gridDim.x;
  const int nwg = gx * gridDim.y;
  int flat = blockIdx.y * gx + blockIdx.x;
  if ((nwg & 7) == 0) flat = (flat & 7) * (nwg >> 3) + (flat >> 3);
  const int m0 = (flat / gx) * 128, n0 = (flat % gx) * 128;
  const int mo = (w & 1) * 64, no = (w >> 1) * 64;

  float4v acc[4][4];
#pragma unroll
  for (int i = 0; i < 4; i++)
#pragma unroll
    for (int j = 0; j < 4; j++) acc[i][j] = (float4v)0.0f;

  // staging: linear LDS dest; source column chunk pre-swizzled so that
  // LDS[row][slot] holds global chunk slot^((row>>1)&3)
  const int srow = w * 32 + (lane >> 2);
  const int scol = ((lane & 3) ^ ((lane >> 3) & 3)) * 8;
  const short* Ag = A + (size_t)(m0 + srow) * K + scol;
  const short* Bg = Bt + (size_t)(n0 + srow) * K + scol;

  // read-side: lane-constant swizzled slot
  const int qsw8 = (quad ^ ((lm >> 1) & 3)) * 8;

  for (int kb = 0; kb < K; kb += 64) {
#pragma unroll
    for (int s = 0; s < 2; s++) {
      short* Al = &As[s][(w * 32) * 32];
      short* Bl = &Bs[s][(w * 32) * 32];
      g2l16(Ag + kb + s * 32, Al);
      g2l16(Ag + kb + s * 32 + (size_t)16 * K, Al + 16 * 32);
      g2l16(Bg + kb + s * 32, Bl);
      g2l16(Bg + kb + s * 32 + (size_t)16 * K, Bl + 16 * 32);
    }
    __syncthreads();

#pragma unroll
    for (int s = 0; s < 2; s++) {
      short8 af[4], bf[4];
#pragma unroll
      for (int i = 0; i < 4; i++)
        af[i] = *(const short8*)&As[s][(mo + i * 16 + lm) * 32 + qsw8];
#pragma unroll
      for (int j = 0; j < 4; j++)
        bf[j] = *(const short8*)&Bs[s][(no + j * 16 + lm) * 32 + qsw8];
#pragma unroll
      for (int i = 0; i < 4; i++)
#pragma unroll
        for (int j = 0; j < 4; j++) {
          if constexpr (OUT == 2)
            acc[i][j] = __builtin_amdgcn_mfma_f32_16x16x32_bf16(bf[j], af[i], acc[i][j], 0, 0, 0);
          else
            acc[i][j] = __builtin_amdgcn_mfma_f32_16x16x32_bf16(af[i], bf[j], acc[i][j], 0, 0, 0);
        }
    }
    __syncthreads();
  }

  if constexpr (OUT == 0) {
#pragma unroll
    for (int i = 0; i < 4; i++)
#pragma unroll
      for (int j = 0; j < 4; j++)
#pragma unroll
        for (int r = 0; r < 4; r++)
          Cf[(size_t)(m0 + mo + i * 16 + quad * 4 + r) * N + n0 + no + j * 16 + lm] =
              acc[i][j][r];
  } else if constexpr (OUT == 1) {  // Q/K tile -> qk[m][1536]
#pragma unroll
    for (int i = 0; i < 4; i++)
#pragma unroll
      for (int j = 0; j < 4; j++)
#pragma unroll
        for (int r = 0; r < 4; r++)
          Cq[(size_t)(m0 + mo + i * 16 + quad * 4 + r) * (2 * HID) + n0 + no + j * 16 + lm] =
              f2b(acc[i][j][r]);
  } else {  // V tile (swapped acc: rows=n/d, cols=m/s) -> vT[b][h][d][s]
    const int b = m0 >> 11;
#pragma unroll
    for (int i = 0; i < 4; i++) {
      const int sG = (m0 & 2047) + mo + i * 16 + lm;
#pragma unroll
      for (int j = 0; j < 4; j++) {
#pragma unroll
        for (int r = 0; r < 4; r++) {
          int col = n0 + no + j * 16 + quad * 4 + r;   // 0..767 (V block local)
          int h = col >> 6, d = col & 63;
          vT[((size_t)(b * NHEAD + h) * HDIM + d) * S_LEN + sG] = f2b(acc[i][j][r]);
        }
      }
    }
  }
}

// ---------------- MFMA flash attention (round-21: in-register P, no Ps LDS) ----
// r13 falsified the cadence theory (72KB LDS -> occ 18% -> -11us); r8's
// 64-key/40KB staging is restored.  The remaining serial-chain cost is the
// Ps LDS round-trip (4x ds_write_b64 + lgkm wait + 2x ds_read_b128 per
// iteration).  Eliminated via swapped QK^T (T12 mechanism, 16x16 analog):
//   * s_acc = mfma(K_frag, Q_frag): P emerges with qrow = col = lane's lm
//     (same aq registers serve as B-operand; A/B fragment layouts are
//     symmetric: lane(quad,lm) gives A[lm][quad*8+j] and B[quad*8+j][lm]).
//   * K staging permutation chosen as key = 8*(ra>>2)+2*(ra&3)+(nt&1)
//     +32*(nt>>1)  (free: folded into the DMA source address) so each lane
//     holds EXACTLY the keys its PV A-fragment needs (32*kb+quad*8+0..7):
//     P goes s_acc -> exp -> pkbf pairs -> PV A-operand, zero cross-lane.
//   * Ps deleted: LDS 40960 -> 32768 (5 blocks/CU capacity).
//   * Output layout & o1 row-sum unchanged (C row=quad*4+r -> qrow, col=lm
//     -> d): epilogue identical to r8.
__global__ __launch_bounds__(256) void attn_mfma(const short* __restrict__ qk,
                                                 const short* __restrict__ vT,
                                                 short* __restrict__ attnout) {
  __shared__ __align__(16) short Ks[2][64 * 64];   // [p][d], p key-permuted, swizzled
  __shared__ __align__(16) short Vt[2][64 * 64];   // [d][key], swizzled

  const int tid = threadIdx.x;
  const int w = tid >> 6, lane = tid & 63;
  const int quad = lane >> 4, lm = lane & 15;
  const int bh = blockIdx.x;
  const int qt = 31 - blockIdx.y;        // longest-first dispatch order
  const int b = bh / NHEAD, h = bh % NHEAD;

  // ---- Q fragments in registers ----
  short8 aq[2];
#pragma unroll
  for (int kb = 0; kb < 2; kb++)
    aq[kb] = *(const short8*)&qk[(size_t)(b * S_LEN + qt * 64 + w * 16 + lm) * (2 * HID) +
                                 h * HDIM + kb * 32 + quad * 8];

  // ---- register constants ----
  const float4v z4 = (float4v)0.0f;       // C operand for first-kb MFMA
  short8 one8;                            // bf16 1.0 broadcast (B-frag of ones)
#pragma unroll
  for (int j = 0; j < 8; j++) one8[j] = (short)0x3F80;

  // ---- per-lane DMA source pointers (inverse swizzle + NEW key permutation
  //      pre-applied; LDS dest linear; bump-by-constant each issue) ----
  const size_t kbase = (size_t)(b * S_LEN) * (2 * HID) + HID + h * HDIM;
  const size_t vbase = (size_t)(b * NHEAD + h) * HDIM * S_LEN;
  const short* kptr[2];
  const short* vptr[2];
#pragma unroll
  for (int i = 0; i < 2; i++) {
    int c = (w * 2 + i) * 64 + lane;       // LDS 16B-chunk index this lane writes
    int row = c >> 3, slot = c & 7;
    int q8 = slot ^ (row & 7);             // inverse-swizzled source chunk
    int ra = row & 15, nt = row >> 4;
    // key permutation making PV A-frag keys lane-local after swapped QK^T:
    int key = 8 * (ra >> 2) + 2 * (ra & 3) + (nt & 1) + 32 * (nt >> 1);
    kptr[i] = qk + kbase + (size_t)key * (2 * HID) + q8 * 8;
    vptr[i] = vT + vbase + (size_t)row * S_LEN + q8 * 8;
  }

#define ISSUE(BUF)                                                    \
  {                                                                   \
    _Pragma("unroll") for (int i = 0; i < 2; i++) {                   \
      g2l16(kptr[i], &Ks[BUF][(w * 2 + i) * 512]);                    \
      g2l16(vptr[i], &Vt[BUF][(w * 2 + i) * 512]);                    \
      kptr[i] += 64 * 2 * HID;                                        \
      vptr[i] += 64;                                                  \
    }                                                                 \
  }

  // ---- hoisted LDS read addressing ----
  const int swx = (lm & 7) << 4;
  const int loff0 = (quad * 16) ^ swx;          // kb=0 lane part
  const int loff1 = (64 + quad * 16) ^ swx;     // kb=1 lane part
  const int rowK = lm << 7;
  const char* KsB = (const char*)&Ks[0][0];
  const char* VtB = (const char*)&Vt[0][0];

  float4v o_acc[4];
#pragma unroll
  for (int nt = 0; nt < 4; nt++) o_acc[nt] = (float4v)0.0f;
  float4v o1 = (float4v)0.0f;                   // P row-sum accumulator

  const int ktmax = qt + 1;
  int cur = 0;

  ISSUE(0);

  for (int kt = 0; kt < ktmax; kt++) {
    // drain our in-flight DMA for buf[cur], and fence buf[cur^1] readers
    asm volatile("s_waitcnt vmcnt(0)" ::: "memory");
    __syncthreads();
    if (kt + 1 < ktmax) ISSUE(cur ^ 1);

    const int coff = cur << 13;
    const char* kB0 = KsB + coff + rowK + loff0;
    const char* kB1 = KsB + coff + rowK + loff1;
    const char* vB0 = VtB + coff + rowK + loff0;
    const char* vB1 = VtB + coff + rowK + loff1;

    // QK^T with SWAPPED operands: P[key][qrow], qrow = col = lane's lm.
    float4v s_acc[4];
    __builtin_amdgcn_s_setprio(1);
#pragma unroll
    for (int nt = 0; nt < 4; nt++) {
      short8 bk = *(const short8*)(kB0 + nt * 2048);
      s_acc[nt] = __builtin_amdgcn_mfma_f32_16x16x32_bf16(bk, aq[0], z4, 0, 0, 0);
    }
#pragma unroll
    for (int nt = 0; nt < 4; nt++) {
      short8 bk = *(const short8*)(kB1 + nt * 2048);
      s_acc[nt] = __builtin_amdgcn_mfma_f32_16x16x32_bf16(bk, aq[1], s_acc[nt], 0, 0, 0);
    }
    __builtin_amdgcn_s_setprio(0);

    // lane(quad,lm) holds P[qrow=w*16+lm][key = 8*quad+2*r+(nt&1)+32*(nt>>1)]
    const bool diag = (kt == qt);
    float e[4][4];
#pragma unroll
    for (int nt = 0; nt < 4; nt++)
#pragma unroll
      for (int r = 0; r < 4; r++) {
        float v = fexp2(s_acc[nt][r]);  // Q pre-scaled by 0.125*log2e
        if (diag && (8 * quad + 2 * r + (nt & 1) + 32 * (nt >> 1) > w * 16 + lm)) v = 0.0f;
        e[nt][r] = v;
      }

    // pack in-register into PV A-fragments (keys 32*kb+quad*8+0..7)
    int4v p0i = {(int)pkbf(e[0][0], e[1][0]), (int)pkbf(e[0][1], e[1][1]),
                 (int)pkbf(e[0][2], e[1][2]), (int)pkbf(e[0][3], e[1][3])};
    int4v p1i = {(int)pkbf(e[2][0], e[3][0]), (int)pkbf(e[2][1], e[3][1]),
                 (int)pkbf(e[2][2], e[3][2]), (int)pkbf(e[2][3], e[3][3])};
    union UU { int4v i; short8 s; };
    UU u0, u1;
    u0.i = p0i;
    u1.i = p1i;
    short8 ap0 = u0.s, ap1 = u1.s;

    __builtin_amdgcn_s_setprio(1);
    o1 = __builtin_amdgcn_mfma_f32_16x16x32_bf16(ap0, one8, o1, 0, 0, 0);
#pragma unroll
    for (int nt = 0; nt < 4; nt++) {
      short8 bv = *(const short8*)(vB0 + nt * 2048);
      o_acc[nt] = __builtin_amdgcn_mfma_f32_16x16x32_bf16(ap0, bv, o_acc[nt], 0, 0, 0);
    }
    o1 = __builtin_amdgcn_mfma_f32_16x16x32_bf16(ap1, one8, o1, 0, 0, 0);
#pragma unroll
    for (int nt = 0; nt < 4; nt++) {
      short8 bv = *(const short8*)(vB1 + nt * 2048);
      o_acc[nt] = __builtin_amdgcn_mfma_f32_16x16x32_bf16(ap1, bv, o_acc[nt], 0, 0, 0);
    }
    __builtin_amdgcn_s_setprio(0);

    cur ^= 1;
  }

#pragma unroll
  for (int r = 0; r < 4; r++) {
    float inv = 1.0f / o1[r];             // row-sum from ones-MFMA (col-uniform)
    int rowg = b * S_LEN + qt * 64 + w * 16 + quad * 4 + r;
#pragma unroll
    for (int nt = 0; nt < 4; nt++)
      attnout[(size_t)rowg * HID + h * HDIM + nt * 16 + lm] =
          f2b(o_acc[nt][r] * inv);
  }
#undef ISSUE
}

extern "C" void kernel_launch(void* const* d_in, const int* in_sizes, int n_in,
                              void* d_out, int out_size, void* d_ws, size_t ws_size,
                              hipStream_t stream) {
  const float* x     = (const float*)d_in[0];
  const float* w_qkv = (const float*)d_in[1];
  const float* w_out = (const float*)d_in[2];
  float* out = (float*)d_out;

  const int M = BATCH * S_LEN;  // 8192
  short* qk     = (short*)d_ws;                       // [8192][1536] bf16
  short* attn   = qk + (size_t)M * 2 * HID;           // [8192][768]  bf16
  short* vT     = attn + (size_t)M * HID;             // [B][NH][64][2048] bf16
  short* xb     = vT + (size_t)M * HID;               // [8192][768]  bf16
  short* wqkvT  = xb + (size_t)M * HID;               // [2304][768]  bf16 (Q rows pre-scaled)
  short* woutT  = wqkvT + (size_t)(3 * HID) * HID;    // [768][768]   bf16

  prepass<<<3648, 256, 0, stream>>>(x, w_qkv, w_out, xb, wqkvT, woutT);

  // Q/K columns (N=1536): nwg = 12*64 = 768 (%8==0)
  gemm_bt<1><<<dim3(2 * HID / 128, M / 128), 256, 0, stream>>>(
      xb, wqkvT, nullptr, qk, nullptr, M, 2 * HID, HID);
  // V columns (N=768), swapped-operand MFMA: nwg = 6*64 = 384 (%8==0)
  gemm_bt<2><<<dim3(HID / 128, M / 128), 256, 0, stream>>>(
      xb, wqkvT + (size_t)(2 * HID) * HID, nullptr, nullptr, vT, M, HID, HID);
  // one q-tile per block; qt = 31-blockIdx.y -> longest blocks first
  attn_mfma<<<dim3(BATCH * NHEAD, 32), 256, 0, stream>>>(qk, vT, attn);
  gemm_bt<0><<<dim3(HID / 128, M / 128), 256, 0, stream>>>(
      attn, woutT, out, nullptr, nullptr, M, HID, HID);
}